// Round 3
// baseline (850.411 us; speedup 1.0000x reference)
//
#include <hip/hip_runtime.h>
#include <math.h>

// B=2, C=32, H=80, W=80, D=80 fp32.
// slice (b,c,h) = contiguous [80 w][80 d] block; 5120 slices, 2560/batch.
// S[b,w,v] = sum_slices X[w][:]·T[v][:];  out_slice = att_b(80x80) @ G_slice.
//
// Per-WAVE async pipelines: global_load_lds (16B) staging, double-buffered,
// counted vmcnt waits (never 0 mid-loop). 8x8 lanes x 10x10 register tile.
// QK LDS chunk [80 rows][16 k] uses a 16B-block rotation swizzle
// (slot = (k4 + (row>>1)) & 3) applied to BOTH the global source address and
// the LDS read address (linear DMA dest) -> 2-way banks max on b128 reads.

#define WW 80
#define DD 80
#define SLICE 6400
#define SPB 2560

__device__ __forceinline__ void gld16(const void* g, void* l) {
  __builtin_amdgcn_global_load_lds(
      (const __attribute__((address_space(1))) void*)g,
      (__attribute__((address_space(3))) void*)l, 16, 0, 0);
}

// ---------------- QK ----------------
__global__ __launch_bounds__(128, 2)
void qk3_kernel(const float* __restrict__ x, const float* __restrict__ xt,
                float* __restrict__ S) {
  __shared__ __align__(16) float lds[2][2][2][1280];  // [wave][par][op][5KB] = 40 KB
  const int tid  = threadIdx.x;
  const int wv   = tid >> 6;
  const int lane = tid & 63;
  const int r    = lane >> 3, c = lane & 7;
  const int bi   = blockIdx.x;                 // 0..1023, 5 slices per block
  const int batch = bi >> 9;

  // wave chunk split of the block's 25 chunks: {13,12}
  const int gc0 = wv ? 13 : 0;
  const int nc  = wv ? 12 : 13;

  long slice_off = (long)(bi * 5 + gc0 / 5) * SLICE;   // in floats
  int ch = gc0 % 5;
  int staged = 0;

  // per-lane staging source pattern: row = 16t + (l>>2); k4 = ((l&3)-(l>>3))&3
  const int k4l = ((lane & 3) - (lane >> 3)) & 3;
  const int lane_off = (lane >> 2) * 320 + k4l * 16;   // bytes

  auto STAGE = [&]() {
    const char* bx = (const char*)(x  + slice_off) + ch * 64 + lane_off;
    const char* bt = (const char*)(xt + slice_off) + ch * 64 + lane_off;
    char* lX = (char*)&lds[wv][staged & 1][0][0];
    char* lT = (char*)&lds[wv][staged & 1][1][0];
#pragma unroll
    for (int t = 0; t < 5; ++t) {
      gld16(bx + t * 5120, lX + t * 1024);
      gld16(bt + t * 5120, lT + t * 1024);
    }
    ++staged;
    if (++ch == 5) { ch = 0; slice_off += SLICE; }
  };

  STAGE(); STAGE();

  float acc[10][10] = {};
  int baseA[10], baseB[10];                    // LDS byte offsets of rows
#pragma unroll
  for (int i = 0; i < 10; ++i) {
    baseA[i] = (r * 10 + i) << 6;
    baseB[i] = (c * 10 + i) << 6;
  }

#pragma unroll 1
  for (int cc = 0; cc < nc; ++cc) {
    if (cc + 1 < nc) asm volatile("s_waitcnt vmcnt(10)" ::: "memory");
    else             asm volatile("s_waitcnt vmcnt(0)"  ::: "memory");
    const char* lX = (const char*)&lds[wv][cc & 1][0][0];
    const char* lT = (const char*)&lds[wv][cc & 1][1][0];
    for (int q = 0; q < 4; ++q) {
      float4 bq[10];
#pragma unroll
      for (int j = 0; j < 10; ++j)
        bq[j] = *(const float4*)(lT + baseB[j] +
                                 (((baseB[j] >> 3) + (q << 4)) & 48));
#pragma unroll
      for (int i = 0; i < 10; ++i) {
        const float4 av = *(const float4*)(lX + baseA[i] +
                                           (((baseA[i] >> 3) + (q << 4)) & 48));
#pragma unroll
        for (int j = 0; j < 10; ++j) {
          acc[i][j] = fmaf(av.x, bq[j].x, acc[i][j]);
          acc[i][j] = fmaf(av.y, bq[j].y, acc[i][j]);
          acc[i][j] = fmaf(av.z, bq[j].z, acc[i][j]);
          acc[i][j] = fmaf(av.w, bq[j].w, acc[i][j]);
        }
      }
    }
    asm volatile("s_waitcnt lgkmcnt(0)" ::: "memory");
    if (staged < nc) STAGE();
  }

  // block reduce (wave1 -> LDS, wave0 adds) then atomics by wave0
  float* flat = &lds[0][0][0][0];
  __syncthreads();
  if (wv == 1) {
#pragma unroll
    for (int i = 0; i < 10; ++i)
#pragma unroll
      for (int p = 0; p < 5; ++p) {
        float2 v; v.x = acc[i][2 * p]; v.y = acc[i][2 * p + 1];
        *(float2*)(flat + (r * 10 + i) * 80 + c * 10 + 2 * p) = v;
      }
  }
  __syncthreads();
  if (wv == 0) {
    float* Sb = S + batch * SLICE;
#pragma unroll
    for (int i = 0; i < 10; ++i)
#pragma unroll
      for (int p = 0; p < 5; ++p) {
        float2 v = *(const float2*)(flat + (r * 10 + i) * 80 + c * 10 + 2 * p);
        atomicAdd(&Sb[(r * 10 + i) * 80 + c * 10 + 2 * p],     acc[i][2 * p]     + v.x);
        atomicAdd(&Sb[(r * 10 + i) * 80 + c * 10 + 2 * p + 1], acc[i][2 * p + 1] + v.y);
      }
  }
}

// ---------------- softmax over v, in place; one wave per row ----------------
__global__ void softmax_kernel(float* __restrict__ S) {
  const int rr = blockIdx.x;           // 0..159 (b*80 + w)
  const int lane = threadIdx.x;        // 0..63
  float* row = S + rr * WW;
  float v0 = (lane < WW) ? row[lane] : -INFINITY;
  float v1 = (lane + 64 < WW) ? row[lane + 64] : -INFINITY;
  float m = fmaxf(v0, v1);
#pragma unroll
  for (int off = 32; off; off >>= 1) m = fmaxf(m, __shfl_xor(m, off));
  float e0 = (lane < WW) ? expf(v0 - m) : 0.f;
  float e1 = (lane + 64 < WW) ? expf(v1 - m) : 0.f;
  float ssum = e0 + e1;
#pragma unroll
  for (int off = 32; off; off >>= 1) ssum += __shfl_xor(ssum, off);
  float inv = 1.f / ssum;
  if (lane < WW) row[lane] = e0 * inv;
  if (lane + 64 < WW) row[lane + 64] = e1 * inv;
}

// ---------------- PV: out_slice = att_b @ G_slice ----------------
__global__ __launch_bounds__(128, 2)
void pv3_kernel(const float* __restrict__ g, const float* __restrict__ att,
                float* __restrict__ out) {
  __shared__ __align__(16) float As[80][82];          // 26240 B, conflict-free rows
  __shared__ __align__(16) float Gb[2][2][1280];      // [wave][par][16v x 80d] 20 KB
  const int tid  = threadIdx.x;
  const int wv   = tid >> 6;
  const int lane = tid & 63;
  const int r    = lane >> 3, c = lane & 7;
  const int bi   = blockIdx.x;                 // 0..1279, 4 slices per block
  const int batch = (bi * 4) / SPB;
  const int s0 = bi * 4 + wv * 2;              // 2 slices per wave

  long slice_off = (long)s0 * SLICE;
  int ch = 0;
  int staged = 0;
  auto STAGE = [&]() {
    const char* bg = (const char*)(g + slice_off) + ch * 5120 + lane * 16;
    char* lG = (char*)&Gb[wv][staged & 1][0];
#pragma unroll
    for (int t = 0; t < 5; ++t) gld16(bg + t * 1024, lG + t * 1024);
    ++staged;
    if (++ch == 5) { ch = 0; slice_off += SLICE; }
  };
  STAGE(); STAGE();

  // stage att once per block (float2: rows are 8B-aligned at stride 82)
  const float* ab = att + batch * SLICE;
  for (int f = tid; f < 3200; f += 128) {
    int row = f / 40, c2 = f - row * 40;
    *(float2*)&As[row][c2 * 2] = *(const float2*)(ab + row * 80 + c2 * 2);
  }
  __syncthreads();   // drains staging too (chunks 0,1 certainly landed)

  int baseAtt[10];
#pragma unroll
  for (int i = 0; i < 10; ++i) baseAtt[i] = (r * 10 + i) * 328;  // 82*4 bytes
  const int colb = c * 8;                       // byte offset of col 2c

  float acc[10][10];
#pragma unroll 1
  for (int sl = 0; sl < 2; ++sl) {
#pragma unroll
    for (int i = 0; i < 10; ++i)
#pragma unroll
      for (int j = 0; j < 10; ++j) acc[i][j] = 0.f;

#pragma unroll 1
    for (int ch5 = 0; ch5 < 5; ++ch5) {
      const int cc = sl * 5 + ch5;
      if (cc < 9) asm volatile("s_waitcnt vmcnt(5)" ::: "memory");
      else        asm volatile("s_waitcnt vmcnt(0)" ::: "memory");
      const char* lG = (const char*)&Gb[wv][cc & 1][0];
      const char* aB = (const char*)&As[0][0] + ch5 * 64;
      for (int vp = 0; vp < 8; ++vp) {
        float2 a2[10];
#pragma unroll
        for (int i = 0; i < 10; ++i)
          a2[i] = *(const float2*)(aB + baseAtt[i] + vp * 8);
        const char* gv0 = lG + vp * 640;
        float2 bA[5], bB[5];
#pragma unroll
        for (int p = 0; p < 5; ++p) {
          bA[p] = *(const float2*)(gv0 + colb + p * 64);
          bB[p] = *(const float2*)(gv0 + 320 + colb + p * 64);
        }
#pragma unroll
        for (int i = 0; i < 10; ++i)
#pragma unroll
          for (int p = 0; p < 5; ++p) {
            acc[i][2 * p]     = fmaf(a2[i].x, bA[p].x, acc[i][2 * p]);
            acc[i][2 * p]     = fmaf(a2[i].y, bB[p].x, acc[i][2 * p]);
            acc[i][2 * p + 1] = fmaf(a2[i].x, bA[p].y, acc[i][2 * p + 1]);
            acc[i][2 * p + 1] = fmaf(a2[i].y, bB[p].y, acc[i][2 * p + 1]);
          }
      }
      asm volatile("s_waitcnt lgkmcnt(0)" ::: "memory");
      if (staged < 10) STAGE();
    }
    // store slice: cols 16p + 2c + {0,1} -> 64B-contiguous per 8-lane group
    float* po = out + (long)(s0 + sl) * SLICE;
#pragma unroll
    for (int i = 0; i < 10; ++i)
#pragma unroll
      for (int p = 0; p < 5; ++p) {
        float2 v; v.x = acc[i][2 * p]; v.y = acc[i][2 * p + 1];
        *(float2*)(po + (r * 10 + i) * 80 + 16 * p + 2 * c) = v;
      }
  }
}

extern "C" void kernel_launch(void* const* d_in, const int* in_sizes, int n_in,
                              void* d_out, int out_size, void* d_ws, size_t ws_size,
                              hipStream_t stream) {
  const float* x_  = (const float*)d_in[0];
  const float* x_t = (const float*)d_in[1];
  const float* g_x = (const float*)d_in[2];
  float* out = (float*)d_out;
  float* S = (float*)d_ws;                    // 2*80*80 fp32 = 51.2 KB

  hipMemsetAsync(S, 0, 2 * SLICE * sizeof(float), stream);
  qk3_kernel<<<dim3(1024), dim3(128), 0, stream>>>(x_, x_t, S);
  softmax_kernel<<<dim3(160), dim3(64), 0, stream>>>(S);
  pv3_kernel<<<dim3(1280), dim3(128), 0, stream>>>(g_x, S, out);
}